// Round 3
// baseline (918.601 us; speedup 1.0000x reference)
//
#include <hip/hip_runtime.h>
#include <hip/hip_bf16.h>

#define N_POINTS 100000
#define K_VOL 27
#define PAIRS 60000
#define TOTALP (K_VOL * PAIRS)          // 1,620,000
#define CCH 64                          // C_IN == C_OUT == 64
#define RANGE 224                       // output rows per block (LDS tile)
#define NRANGE ((N_POINTS + RANGE - 1) / RANGE)   // 447
#define NBK (NRANGE * K_VOL)            // 12069 buckets
#define ASTRIDE 68                      // padded LDS row stride (dwords): 272B, 16B-aligned, bank-spread
#define MWAVES 8                        // main kernel: 512 threads

// ws layout (byte offsets, all 16-aligned). Total ~13.4 MB.
#define CNT_OFF    0u
#define STARTS_OFF 65536u
#define CURS_OFF   131072u
#define WPK_OFF    196608u              // packed weights: 27*8*64*16 B = 221184
#define REC_OFF    417792u              // records: 1.62M * 8 B = 12,960,000

typedef __bf16 bf16x8 __attribute__((ext_vector_type(8)));
typedef float f32x4 __attribute__((ext_vector_type(4)));

__device__ __forceinline__ bf16x8 cvt8(float4 a, float4 b) {
  bf16x8 f;
  f[0] = (__bf16)a.x; f[1] = (__bf16)a.y; f[2] = (__bf16)a.z; f[3] = (__bf16)a.w;
  f[4] = (__bf16)b.x; f[5] = (__bf16)b.y; f[6] = (__bf16)b.z; f[7] = (__bf16)b.w;
  return f;
}

// ---- Stage 0: pack W[k] into per-lane MFMA B-fragments (bf16), 16B per frag.
// layout: wpk[(k*8 + f)*64 + lane], f = nt*2 + s
__global__ __launch_bounds__(256) void pack_w_kernel(
    const float* __restrict__ weight, bf16x8* __restrict__ wpk) {
  int t = blockIdx.x * 256 + threadIdx.x;       // 27*8*64 = 13824 threads exact
  int lane = t & 63, f = (t >> 6) & 7, k = t >> 9;
  int col = lane & 15, quad = lane >> 4;
  int nt = f >> 1, s = f & 1;
  const float* Wk = weight + k * (CCH * CCH);
  bf16x8 v;
#pragma unroll
  for (int j = 0; j < 8; ++j)
    v[j] = (__bf16)Wk[(s * 32 + quad * 8 + j) * CCH + nt * 16 + col];
  wpk[(k * 8 + f) * 64 + lane] = v;
}

// ---- Stage 1: zero bucket counters (ws is poisoned 0xAA every call)
__global__ __launch_bounds__(256) void zero_cnt_kernel(unsigned* __restrict__ cnt) {
  int t = blockIdx.x * 256 + threadIdx.x;
  if (t < NBK) cnt[t] = 0;
}

// ---- Stage 2: histogram pairs into (range, k) buckets
__global__ __launch_bounds__(256) void hist_kernel(
    const int* __restrict__ out_map, unsigned* __restrict__ cnt) {
  int t = blockIdx.x * 256 + threadIdx.x;
  if (t >= TOTALP) return;
  unsigned orow = (unsigned)out_map[t];
  unsigned k = (unsigned)t / PAIRS;
  unsigned bucket = (orow / RANGE) * K_VOL + k;
  atomicAdd(&cnt[bucket], 1u);
}

// ---- Stage 3: exclusive scan of counts -> starts; zero cursors. One block.
#define SCHUNK 12                        // 12*1024 = 12288 >= 12069
__global__ __launch_bounds__(1024) void scan_kernel(
    const unsigned* __restrict__ cnt, unsigned* __restrict__ starts,
    unsigned* __restrict__ cursors) {
  __shared__ unsigned ssum[1024];
  int t = threadIdx.x;
  unsigned local = 0;
  int base = t * SCHUNK;
#pragma unroll
  for (int i = 0; i < SCHUNK; ++i) {
    int b = base + i;
    if (b < NBK) local += cnt[b];
  }
  ssum[t] = local;
  __syncthreads();
  for (int off = 1; off < 1024; off <<= 1) {
    unsigned v = (t >= off) ? ssum[t - off] : 0u;
    __syncthreads();
    ssum[t] += v;
    __syncthreads();
  }
  unsigned run = ssum[t] - local;   // exclusive prefix
#pragma unroll
  for (int i = 0; i < SCHUNK; ++i) {
    int b = base + i;
    if (b < NBK) {
      starts[b] = run;
      cursors[b] = 0;
      run += cnt[b];
    }
  }
  if (t == 1023) starts[NBK] = run;  // == TOTALP
}

// ---- Stage 4: scatter pair records (in_row, out_row) into packed buckets
__global__ __launch_bounds__(256) void scatter_kernel(
    const int* __restrict__ in_map, const int* __restrict__ out_map,
    const unsigned* __restrict__ starts, unsigned* __restrict__ cursors,
    uint2* __restrict__ records) {
  int t = blockIdx.x * 256 + threadIdx.x;
  if (t >= TOTALP) return;
  unsigned irow = (unsigned)in_map[t];
  unsigned orow = (unsigned)out_map[t];
  unsigned k = (unsigned)t / PAIRS;
  unsigned bucket = (orow / RANGE) * K_VOL + k;
  unsigned slot = atomicAdd(&cursors[bucket], 1u);
  records[starts[bucket] + slot] = make_uint2(irow, orow);
}

// ---- Stage 5: main — per-range LDS accumulation, MFMA per k-segment, flush.
__global__ __launch_bounds__(512, 4) void main_kernel(
    const float* __restrict__ input,     // [N, 64]
    const float* __restrict__ bias,      // [64]
    const unsigned* __restrict__ starts, // [NBK+1]
    const uint2* __restrict__ records,   // [TOTALP]
    const bf16x8* __restrict__ wpk,      // packed B-frags
    float* __restrict__ out)             // [N, 64]
{
  __shared__ float acc_lds[RANGE * ASTRIDE];   // 60928 B
  const int range = blockIdx.x;
  const int rbase = range * RANGE;
  const int tid = threadIdx.x, lane = tid & 63, wave = tid >> 6;
  const int col = lane & 15, quad = lane >> 4;

  // init LDS tile to bias (flush adds nothing else)
  {
    float4 b4[1];
    for (int i = tid; i < RANGE * 16; i += 512) {
      int r = i >> 4, c4 = i & 15;
      b4[0] = ((const float4*)bias)[c4];
      *(float4*)&acc_lds[r * ASTRIDE + c4 * 4] = b4[0];
    }
  }
  __syncthreads();

  // each wave owns k = wave, wave+8, wave+16, wave+24 (<27)
  for (int k = wave; k < K_VOL; k += MWAVES) {
    // B fragments from packed ws (8 x 16B coalesced loads)
    bf16x8 bfrag[4][2];
#pragma unroll
    for (int f = 0; f < 8; ++f)
      bfrag[f >> 1][f & 1] = wpk[(k * 8 + f) * 64 + lane];

    const unsigned b0 = starts[range * K_VOL + k];
    const unsigned b1 = starts[range * K_VOL + k + 1];  // contiguous global order
    const int n = (int)(b1 - b0);

    for (int t = 0; t < n; t += 16) {
      // lane m = col loads record t+m (all quads replicate)
      bool vld = (t + col) < n;
      uint2 rec = records[b0 + (vld ? (unsigned)(t + col) : 0u)];

      const float* row = input + (size_t)rec.x * CCH + quad * 8;
      float4 a0 = *(const float4*)(row);
      float4 a1 = *(const float4*)(row + 4);
      float4 a2 = *(const float4*)(row + 32);
      float4 a3 = *(const float4*)(row + 36);
      bf16x8 af0 = cvt8(a0, a1);          // ci = quad*8 + j
      bf16x8 af1 = cvt8(a2, a3);          // ci = 32 + quad*8 + j

      f32x4 accv[4];
#pragma unroll
      for (int nt = 0; nt < 4; ++nt) {
        accv[nt] = (f32x4){0.f, 0.f, 0.f, 0.f};
        accv[nt] = __builtin_amdgcn_mfma_f32_16x16x32_bf16(af0, bfrag[nt][0],
                                                           accv[nt], 0, 0, 0);
        accv[nt] = __builtin_amdgcn_mfma_f32_16x16x32_bf16(af1, bfrag[nt][1],
                                                           accv[nt], 0, 0, 0);
      }

      // scatter into LDS: C/D row m = quad*4+r (held by lane m), col = nt*16+col
      int ol = (int)rec.y - rbase;        // out_local of MY record (m = col)
#pragma unroll
      for (int r = 0; r < 4; ++r) {
        int olr = __shfl(ol, quad * 4 + r, 64);
        if (t + quad * 4 + r < n) {
          float* dst = &acc_lds[olr * ASTRIDE + col];
#pragma unroll
          for (int nt = 0; nt < 4; ++nt)
            atomicAdd(dst + nt * 16, accv[nt][r]);
        }
      }
    }
  }

  __syncthreads();
  // flush: plain coalesced float4 stores
  for (int i = tid; i < RANGE * 16; i += 512) {
    int r = i >> 4, c4 = i & 15;
    int row = rbase + r;
    if (row < N_POINTS)
      ((float4*)&out[(size_t)row * CCH])[c4] =
          *(const float4*)&acc_lds[r * ASTRIDE + c4 * 4];
  }
}

extern "C" void kernel_launch(void* const* d_in, const int* in_sizes, int n_in,
                              void* d_out, int out_size, void* d_ws,
                              size_t ws_size, hipStream_t stream) {
  const float* input   = (const float*)d_in[0];
  const float* weight  = (const float*)d_in[1];
  const float* bias    = (const float*)d_in[2];
  const int*   in_map  = (const int*)d_in[3];
  const int*   out_map = (const int*)d_in[4];
  float* out = (float*)d_out;

  char* ws = (char*)d_ws;
  unsigned* cnt     = (unsigned*)(ws + CNT_OFF);
  unsigned* starts  = (unsigned*)(ws + STARTS_OFF);
  unsigned* cursors = (unsigned*)(ws + CURS_OFF);
  bf16x8*   wpk     = (bf16x8*)(ws + WPK_OFF);
  uint2*    records = (uint2*)(ws + REC_OFF);

  pack_w_kernel<<<54, 256, 0, stream>>>(weight, wpk);                 // 13824 thr
  zero_cnt_kernel<<<(NBK + 255) / 256, 256, 0, stream>>>(cnt);
  hist_kernel<<<(TOTALP + 255) / 256, 256, 0, stream>>>(out_map, cnt);
  scan_kernel<<<1, 1024, 0, stream>>>(cnt, starts, cursors);
  scatter_kernel<<<(TOTALP + 255) / 256, 256, 0, stream>>>(in_map, out_map,
                                                           starts, cursors,
                                                           records);
  main_kernel<<<NRANGE, 512, 0, stream>>>(input, bias, starts, records, wpk,
                                          out);
}

// Round 5
// 421.289 us; speedup vs baseline: 2.1805x; 2.1805x over previous
//
#include <hip/hip_runtime.h>
#include <hip/hip_bf16.h>
#include <hip/hip_fp16.h>

#define N_POINTS 100000
#define K_VOL 27
#define PAIRS 60000
#define CCH 64                     // C_IN == C_OUT == 64
#define DTILES (PAIRS / 32)        // 1875 double-tiles of 32 pairs (exact)
#define BX 76                      // grid (BX, 27) = 2052 blocks
#define NWAVES 4                   // 256 threads

typedef __bf16 bf16x8 __attribute__((ext_vector_type(8)));
typedef float f32x4 __attribute__((ext_vector_type(4)));

// ---- packed f16 atomic add: prefer unsafeAtomicAdd (guaranteed native
// global_atomic_pk_add_f16), SFINAE-fallback to atomicAdd(__half2*).
template <typename T>
__device__ __forceinline__ auto pk_add_impl(T* p, T v, int)
    -> decltype(unsafeAtomicAdd(p, v), void()) {
  unsafeAtomicAdd(p, v);
}
template <typename T>
__device__ __forceinline__ void pk_add_impl(T* p, T v, long) {
  atomicAdd(p, v);
}
__device__ __forceinline__ void pk_add(__half2* p, __half2 v) {
  pk_add_impl(p, v, 0);
}

// ---- zero the f16 accumulator scratch (ws is poisoned 0xAA every call)
__global__ __launch_bounds__(256) void zero_acc_kernel(float4* __restrict__ acc4) {
  int tid = blockIdx.x * 256 + threadIdx.x;   // 800000 float4s = 12.8 MB
  acc4[tid] = make_float4(0.f, 0.f, 0.f, 0.f);
}

// ---- finalize: out[row][c] = float(acc[row][c]) + bias[c]
__global__ __launch_bounds__(256) void finalize_kernel(
    const __half2* __restrict__ acc2, const float* __restrict__ bias,
    float* __restrict__ out) {
  int tid = blockIdx.x * 256 + threadIdx.x;   // over N_POINTS*16 float4s
  int c4 = tid & 15;
  const __half2* p = acc2 + (size_t)(tid >> 4) * 32 + c4 * 2;
  float2 f0 = __half22float2(p[0]);
  float2 f1 = __half22float2(p[1]);
  float4 b = ((const float4*)bias)[c4];
  ((float4*)out)[tid] =
      make_float4(f0.x + b.x, f0.y + b.y, f1.x + b.z, f1.y + b.w);
}

__device__ __forceinline__ bf16x8 cvt8(float4 a, float4 b) {
  bf16x8 f;
  f[0] = (__bf16)a.x; f[1] = (__bf16)a.y; f[2] = (__bf16)a.z; f[3] = (__bf16)a.w;
  f[4] = (__bf16)b.x; f[5] = (__bf16)b.y; f[6] = (__bf16)b.z; f[7] = (__bf16)b.w;
  return f;
}

__global__ __launch_bounds__(256, 4) void spconv_kernel(
    const float* __restrict__ input,   // [N, 64]
    const float* __restrict__ weight,  // [27, 64, 64]  (ci, co)
    const int* __restrict__ in_map,    // [27, PAIRS]
    const int* __restrict__ out_map,   // [27, PAIRS]
    __half2* __restrict__ acc2)        // [N, 32] half2  (f16 accumulator)
{
  const int k    = blockIdx.y;
  const int lane = threadIdx.x & 63;
  const int wave = threadIdx.x >> 6;
  const int col  = lane & 15;
  const int quad = lane >> 4;

  // ---- B fragments, PERMUTED channel map: abstract n-index nt*16+col maps to
  // physical co = col*4 + nt, so this lane's 4 accumulators (nt=0..3) are the
  // 4 consecutive channels col*4 .. col*4+3 -> two pk_add_f16 per (lane, row).
  const float* Wk = weight + k * (CCH * CCH);
  bf16x8 bfrag[4][2];
#pragma unroll
  for (int nt = 0; nt < 4; ++nt) {
    int co = col * 4 + nt;
#pragma unroll
    for (int s = 0; s < 2; ++s) {
      int ci0 = s * 32 + quad * 8;
      bf16x8 f;
#pragma unroll
      for (int j = 0; j < 8; ++j)
        f[j] = (__bf16)Wk[(ci0 + j) * CCH + co];
      bfrag[nt][s] = f;
    }
  }

  const int* im = in_map + k * PAIRS;
  const int* om = out_map + k * PAIRS;

  for (int t = blockIdx.x * NWAVES + wave; t < DTILES; t += BX * NWAVES) {
    const int pb = t * 32;

    // ---- issue all independent loads up front
    int rinA = im[pb + col];
    int rinB = im[pb + 16 + col];
    int orA[4], orB[4];
#pragma unroll
    for (int r = 0; r < 4; ++r) {
      orA[r] = om[pb + quad * 4 + r];
      orB[r] = om[pb + 16 + quad * 4 + r];
    }

    const float* rowA = input + (long)rinA * CCH + quad * 8;
    const float* rowB = input + (long)rinB * CCH + quad * 8;
    float4 a0 = *(const float4*)(rowA);
    float4 a1 = *(const float4*)(rowA + 4);
    float4 a2 = *(const float4*)(rowA + 32);
    float4 a3 = *(const float4*)(rowA + 36);
    float4 b0 = *(const float4*)(rowB);
    float4 b1 = *(const float4*)(rowB + 4);
    float4 b2 = *(const float4*)(rowB + 32);
    float4 b3 = *(const float4*)(rowB + 36);

    // A[m=pair][k=ci]: m = lane&15, ci = s*32 + quad*8 + j
    bf16x8 afA0 = cvt8(a0, a1), afA1 = cvt8(a2, a3);
    bf16x8 afB0 = cvt8(b0, b1), afB1 = cvt8(b2, b3);

    f32x4 accA[4], accB[4];
#pragma unroll
    for (int nt = 0; nt < 4; ++nt) {
      accA[nt] = (f32x4){0.f, 0.f, 0.f, 0.f};
      accB[nt] = (f32x4){0.f, 0.f, 0.f, 0.f};
      accA[nt] = __builtin_amdgcn_mfma_f32_16x16x32_bf16(afA0, bfrag[nt][0],
                                                         accA[nt], 0, 0, 0);
      accA[nt] = __builtin_amdgcn_mfma_f32_16x16x32_bf16(afA1, bfrag[nt][1],
                                                         accA[nt], 0, 0, 0);
      accB[nt] = __builtin_amdgcn_mfma_f32_16x16x32_bf16(afB0, bfrag[nt][0],
                                                         accB[nt], 0, 0, 0);
      accB[nt] = __builtin_amdgcn_mfma_f32_16x16x32_bf16(afB1, bfrag[nt][1],
                                                         accB[nt], 0, 0, 0);
    }

    // ---- scatter-add: row = om[quad*4+r]; lane covers channels col*4..col*4+3
    // -> two packed-f16 atomics per (lane, row) = 51.84M ops total (was 103.7M)
#pragma unroll
    for (int r = 0; r < 4; ++r) {
      __half2* pA = acc2 + (size_t)orA[r] * 32 + col * 2;
      __half2* pB = acc2 + (size_t)orB[r] * 32 + col * 2;
      pk_add(pA,     __floats2half2_rn(accA[0][r], accA[1][r]));
      pk_add(pA + 1, __floats2half2_rn(accA[2][r], accA[3][r]));
      pk_add(pB,     __floats2half2_rn(accB[0][r], accB[1][r]));
      pk_add(pB + 1, __floats2half2_rn(accB[2][r], accB[3][r]));
    }
  }
}

extern "C" void kernel_launch(void* const* d_in, const int* in_sizes, int n_in,
                              void* d_out, int out_size, void* d_ws,
                              size_t ws_size, hipStream_t stream) {
  const float* input   = (const float*)d_in[0];
  const float* weight  = (const float*)d_in[1];
  const float* bias    = (const float*)d_in[2];
  const int*   in_map  = (const int*)d_in[3];
  const int*   out_map = (const int*)d_in[4];
  float* out = (float*)d_out;

  __half2* acc2 = (__half2*)d_ws;            // 100000*64 f16 = 12.8 MB

  zero_acc_kernel<<<3125, 256, 0, stream>>>((float4*)d_ws);  // 800000 float4s

  dim3 grid(BX, K_VOL);
  spconv_kernel<<<grid, 256, 0, stream>>>(input, weight, in_map, out_map, acc2);

  finalize_kernel<<<(N_POINTS * 16) / 256, 256, 0, stream>>>(acc2, bias, out);
}